// Round 3
// baseline (1229.035 us; speedup 1.0000x reference)
//
#include <hip/hip_runtime.h>

// ---------------- problem constants ----------------
#define N_TOK 8192      // B*S tokens
#define H_DIM 1024
#define I_DIM 2048
#define N_EXP 8
#define TOPK  2
#define CAP   17408     // 16384 + 8*128 (per-expert padding to 128)
#define MT_MAX 136      // CAP / 128

// ---------------- workspace layout (bytes) ----------------
#define OFF_TOPK_I 0u          // 16384 i32
#define OFF_TOPK_W 65536u      // 16384 f32
#define OFF_COUNTS 131072u     // 8 i32
#define OFF_LOAD   131104u     // 8 f32
#define OFF_CURSOR 131136u     // 8 i32
#define OFF_PO     131168u     // 16 i32
#define OFF_TILE_E 131232u     // 152 i32 (136 used)
#define OFF_BTOK   131840u     // 17408 i32
#define OFF_BW     201472u     // 17408 f32
#define CTRL_BYTES 271104u
#define OFF_FLAG   271104u     // 1 i32 (written by k_detect every call; no memset needed)
#define OFF_WGT  1048576u                      // 8*2048*1024*2 = 33554432
#define OFF_WUT  (OFF_WGT + 33554432u)
#define OFF_WDT  (OFF_WUT + 33554432u)
#define OFF_HB   (OFF_WDT + 33554432u)         // 17408*2048*2 = 71303168
// y f32 accumulator reuses the WGT region (dead after gemm1)

typedef __attribute__((ext_vector_type(8))) short bf16x8;
typedef __attribute__((ext_vector_type(8))) unsigned short u16x8;
typedef __attribute__((ext_vector_type(4))) float f32x4;

__device__ __forceinline__ float bf2f(unsigned short b) {
  union { unsigned int u; float f; } v; v.u = ((unsigned int)b) << 16; return v.f;
}
__device__ __forceinline__ unsigned short f2bf(float f) {
  union { float f; unsigned int u; } v; v.f = f;
  unsigned int r = (v.u + 0x7FFFu + ((v.u >> 16) & 1u)) >> 16;
  return (unsigned short)r;
}
__device__ __forceinline__ u16x8 pack8(float4 a, float4 b) {
  u16x8 r;
  r[0] = f2bf(a.x); r[1] = f2bf(a.y); r[2] = f2bf(a.z); r[3] = f2bf(a.w);
  r[4] = f2bf(b.x); r[5] = f2bf(b.y); r[6] = f2bf(b.z); r[7] = f2bf(b.w);
  return r;
}
__device__ __forceinline__ f32x4 mfma32(bf16x8 a, bf16x8 b, f32x4 c) {
  return __builtin_amdgcn_mfma_f32_16x16x32_bf16(a, b, c, 0, 0, 0);
}

// ---------------- K0: input dtype detector ----------------
// True f32 normal data -> |v| in (1e-20, 1e6). bf16 data reinterpreted as f32
// has exponent bits built from bf16 exponent LSBs -> |v| ~ 1e36..1e38 (insane).
__global__ void k_detect(const unsigned int* __restrict__ xw, int* __restrict__ dflag) {
  int lane = threadIdx.x;           // 64 threads, 1 block
  union { unsigned int u; float f; } v; v.u = xw[lane];
  float a = fabsf(v.f);
  bool sane = (v.f == 0.0f) || (a > 1e-20f && a < 1e6f);
  unsigned long long m = __ballot(sane);
  if (lane == 0) *dflag = (__popcll(m) >= 32) ? 1 : 0;   // 1 = f32 inputs
}

// ---------------- K2: tiled transpose of the 3 weight tensors -> bf16 ----------------
// w_gate/w_up [e][1024][2048] -> T [e][2048][1024];  w_down [e][2048][1024] -> T [e][1024][2048]
__global__ __launch_bounds__(256) void k_transpose(
    const void* __restrict__ wg, const void* __restrict__ wu, const void* __restrict__ wd,
    unsigned short* __restrict__ wgT, unsigned short* __restrict__ wuT,
    unsigned short* __restrict__ wdT, const int* __restrict__ dflag)
{
  __shared__ unsigned short lds[64][65];
  bool isf = (*dflag != 0);
  int bid = blockIdx.x;
  int m = bid / 4096; int rem = bid % 4096;
  const void* src; unsigned short* dst; int R, C;
  if (m == 0)      { src = wg; dst = wgT; R = 1024; C = 2048; }
  else if (m == 1) { src = wu; dst = wuT; R = 1024; C = 2048; }
  else             { src = wd; dst = wdT; R = 2048; C = 1024; }
  int e = rem / 512; int trem = rem % 512;
  int tcc = C / 64;
  int r0 = (trem / tcc) * 64, c0 = (trem % tcc) * 64;
  size_t ebase = (size_t)e * R * C;
  dst += ebase;
  int tid = threadIdx.x;
  int lr = tid >> 3;            // 0..31
  int lc = (tid & 7) * 8;       // 0..56
#pragma unroll
  for (int p = 0; p < 2; ++p) {
    int row = p * 32 + lr;
    size_t off = ebase + (size_t)(r0 + row) * C + c0 + lc;
    unsigned short tmp[8];
    if (isf) {
      const float* sf = (const float*)src;
      float4 q0 = *(const float4*)&sf[off];
      float4 q1 = *(const float4*)&sf[off + 4];
      *(u16x8*)tmp = pack8(q0, q1);
    } else {
      const unsigned short* ss = (const unsigned short*)src;
      *(u16x8*)tmp = *(const u16x8*)&ss[off];
    }
#pragma unroll
    for (int j = 0; j < 8; ++j) lds[row][lc + j] = tmp[j];
  }
  __syncthreads();
#pragma unroll
  for (int p = 0; p < 2; ++p) {
    int drow = p * 32 + lr;     // local c index
    unsigned short tmp[8];
#pragma unroll
    for (int j = 0; j < 8; ++j) tmp[j] = lds[lc + j][drow];
    *(u16x8*)&dst[(size_t)(c0 + drow) * R + r0 + lc] = *(const u16x8*)tmp;
  }
}

// ---------------- K3: router (1 wave per token) ----------------
__global__ __launch_bounds__(256) void k_router(
    const void* __restrict__ x, const void* __restrict__ gw,
    int* __restrict__ topk_i, float* __restrict__ topk_w,
    int* __restrict__ counts, float* __restrict__ loadw, const int* __restrict__ dflag)
{
  bool isf = (*dflag != 0);
  int wave = threadIdx.x >> 6, lane = threadIdx.x & 63;
  int t = blockIdx.x * 4 + wave;
  float acc[8];
#pragma unroll
  for (int e = 0; e < 8; ++e) acc[e] = 0.f;
  if (isf) {
    const float* xr = (const float*)x + (size_t)t * H_DIM;
    const float* gwf = (const float*)gw;
    for (int h = lane; h < H_DIM; h += 64) {
      float xv = xr[h];
      float4 g0 = *(const float4*)&gwf[h * 8];
      float4 g1 = *(const float4*)&gwf[h * 8 + 4];
      acc[0] += xv * g0.x; acc[1] += xv * g0.y; acc[2] += xv * g0.z; acc[3] += xv * g0.w;
      acc[4] += xv * g1.x; acc[5] += xv * g1.y; acc[6] += xv * g1.z; acc[7] += xv * g1.w;
    }
  } else {
    const unsigned short* xr = (const unsigned short*)x + (size_t)t * H_DIM;
    const unsigned short* gws = (const unsigned short*)gw;
    for (int h = lane; h < H_DIM; h += 64) {
      float xv = bf2f(xr[h]);
      u16x8 gv = *(const u16x8*)(gws + h * 8);
#pragma unroll
      for (int e = 0; e < 8; ++e) acc[e] += xv * bf2f(gv[e]);
    }
  }
#pragma unroll
  for (int off = 32; off > 0; off >>= 1) {
#pragma unroll
    for (int e = 0; e < 8; ++e) acc[e] += __shfl_xor(acc[e], off);
  }
  if (lane == 0) {
    float m = acc[0];
#pragma unroll
    for (int e = 1; e < 8; ++e) m = fmaxf(m, acc[e]);
    float p[8], s = 0.f;
#pragma unroll
    for (int e = 0; e < 8; ++e) { p[e] = __expf(acc[e] - m); s += p[e]; }
    float inv = 1.f / s;
#pragma unroll
    for (int e = 0; e < 8; ++e) p[e] *= inv;
    int i1 = 0;
#pragma unroll
    for (int e = 1; e < 8; ++e) if (p[e] > p[i1]) i1 = e;   // strict > = lowest-index ties
    int i2 = (i1 == 0) ? 1 : 0;
#pragma unroll
    for (int e = 0; e < 8; ++e) if (e != i1 && p[e] > p[i2]) i2 = e;
    float p1 = p[i1], p2 = p[i2];
    float rn = 1.f / (p1 + p2);
    topk_i[t * 2]     = i1; topk_i[t * 2 + 1] = i2;
    topk_w[t * 2]     = p1 * rn; topk_w[t * 2 + 1] = p2 * rn;
    atomicAdd(&counts[i1], 1); atomicAdd(&counts[i2], 1);
    atomicAdd(&loadw[i1], p1); atomicAdd(&loadw[i2], p2);
  }
}

// ---------------- K4: padded offsets + tile->expert map ----------------
__global__ __launch_bounds__(256) void k_offsets(const int* __restrict__ counts,
                                                 int* __restrict__ po, int* __restrict__ tile_e)
{
  __shared__ int spo[9];
  if (threadIdx.x == 0) {
    int a = 0;
    for (int e = 0; e < 8; ++e) { spo[e] = a; po[e] = a; a += (counts[e] + 127) & ~127; }
    spo[8] = a; po[8] = a;
  }
  __syncthreads();
  int mt = threadIdx.x;
  if (mt < MT_MAX) {
    int te = -1, beg = mt * 128;
    if (beg < spo[8]) {
      for (int e = 0; e < 8; ++e) if (beg >= spo[e] && beg < spo[e + 1]) te = e;
    }
    tile_e[mt] = te;
  }
}

// ---------------- K5: bucket fill ----------------
__global__ __launch_bounds__(256) void k_bucket(
    const int* __restrict__ topk_i, const float* __restrict__ topk_w,
    const int* __restrict__ po, int* __restrict__ cursor,
    int* __restrict__ btok, float* __restrict__ bw)
{
  int idx = blockIdx.x * 256 + threadIdx.x;   // < N_TOK*TOPK
  int t = idx >> 1;
  int e = topk_i[idx];
  float w = topk_w[idx];
  int slot = po[e] + atomicAdd(&cursor[e], 1);
  btok[slot] = t;
  bw[slot] = w;
}

// ---------------- K6: grouped GEMM1, fused gate+up+SiLU -> hbuf bf16 ----------------
__global__ __launch_bounds__(256, 2) void k_gemm1(
    const void* __restrict__ x,
    const unsigned short* __restrict__ wgT, const unsigned short* __restrict__ wuT,
    const int* __restrict__ btok, const int* __restrict__ tile_e,
    unsigned short* __restrict__ hbuf, const int* __restrict__ dflag)
{
  int mt = blockIdx.x, nt = blockIdx.y;
  int e = tile_e[mt];
  if (e < 0) return;
  bool isf = (*dflag != 0);
  __shared__ unsigned short As[128 * 32];
  __shared__ unsigned short Bg[128 * 32];
  __shared__ unsigned short Bu[128 * 32];
  int tid = threadIdx.x;
  int wave = tid >> 6, lane = tid & 63;
  int wm = wave >> 1, wn = wave & 1;
  int quad = lane >> 4, l16 = lane & 15;

  int r0 = tid >> 2, r1 = 64 + (tid >> 2);
  int ko = (tid & 3) * 8;
  int t0 = btok[mt * 128 + r0]; t0 = t0 < 0 ? 0 : (t0 > N_TOK - 1 ? N_TOK - 1 : t0);
  int t1 = btok[mt * 128 + r1]; t1 = t1 < 0 ? 0 : (t1 > N_TOK - 1 ? N_TOK - 1 : t1);
  size_t offA0 = (size_t)t0 * H_DIM + ko;
  size_t offA1 = (size_t)t1 * H_DIM + ko;
  const unsigned short* bgb = wgT + (size_t)e * I_DIM * H_DIM;
  const unsigned short* bub = wuT + (size_t)e * I_DIM * H_DIM;
  const unsigned short* gG0 = bgb + (size_t)(nt * 128 + r0) * H_DIM + ko;
  const unsigned short* gG1 = bgb + (size_t)(nt * 128 + r1) * H_DIM + ko;
  const unsigned short* gU0 = bub + (size_t)(nt * 128 + r0) * H_DIM + ko;
  const unsigned short* gU1 = bub + (size_t)(nt * 128 + r1) * H_DIM + ko;

  f32x4 accG[4][4], accU[4][4];
  f32x4 z = {0.f, 0.f, 0.f, 0.f};
#pragma unroll
  for (int i = 0; i < 4; ++i)
#pragma unroll
    for (int j = 0; j < 4; ++j) { accG[i][j] = z; accU[i][j] = z; }

  for (int k0 = 0; k0 < H_DIM; k0 += 32) {
    u16x8 va0, va1;
    if (isf) {
      const float* xf = (const float*)x;
      float4 a0 = *(const float4*)&xf[offA0 + k0];
      float4 a1 = *(const float4*)&xf[offA0 + k0 + 4];
      float4 b0 = *(const float4*)&xf[offA1 + k0];
      float4 b1 = *(const float4*)&xf[offA1 + k0 + 4];
      va0 = pack8(a0, a1); va1 = pack8(b0, b1);
    } else {
      const unsigned short* xs = (const unsigned short*)x;
      va0 = *(const u16x8*)&xs[offA0 + k0];
      va1 = *(const u16x8*)&xs[offA1 + k0];
    }
    u16x8 vg0 = *(const u16x8*)(gG0 + k0);
    u16x8 vg1 = *(const u16x8*)(gG1 + k0);
    u16x8 vu0 = *(const u16x8*)(gU0 + k0);
    u16x8 vu1 = *(const u16x8*)(gU1 + k0);
    *(u16x8*)&As[tid * 8]        = va0;
    *(u16x8*)&As[2048 + tid * 8] = va1;
    *(u16x8*)&Bg[tid * 8]        = vg0;
    *(u16x8*)&Bg[2048 + tid * 8] = vg1;
    *(u16x8*)&Bu[tid * 8]        = vu0;
    *(u16x8*)&Bu[2048 + tid * 8] = vu1;
    __syncthreads();
    bf16x8 af[4];
#pragma unroll
    for (int i = 0; i < 4; ++i)
      af[i] = *(const bf16x8*)&As[(wm * 64 + i * 16 + l16) * 32 + quad * 8];
#pragma unroll
    for (int j = 0; j < 4; ++j) {
      bf16x8 vg = *(const bf16x8*)&Bg[(wn * 64 + j * 16 + l16) * 32 + quad * 8];
      bf16x8 vu = *(const bf16x8*)&Bu[(wn * 64 + j * 16 + l16) * 32 + quad * 8];
#pragma unroll
      for (int i = 0; i < 4; ++i) {
        accG[i][j] = mfma32(af[i], vg, accG[i][j]);
        accU[i][j] = mfma32(af[i], vu, accU[i][j]);
      }
    }
    __syncthreads();
  }
#pragma unroll
  for (int i = 0; i < 4; ++i) {
#pragma unroll
    for (int r = 0; r < 4; ++r) {
      int row = mt * 128 + wm * 64 + i * 16 + quad * 4 + r;
      size_t base = (size_t)row * I_DIM + nt * 128 + wn * 64 + l16;
#pragma unroll
      for (int j = 0; j < 4; ++j) {
        float g = accG[i][j][r], u = accU[i][j][r];
        float sg = g / (1.f + __expf(-g));    // SiLU
        hbuf[base + j * 16] = f2bf(sg * u);
      }
    }
  }
}

// ---------------- K7: grouped GEMM2, scatter w*val into f32 y accumulator ----------------
__global__ __launch_bounds__(256, 2) void k_gemm2(
    const unsigned short* __restrict__ hbuf, const unsigned short* __restrict__ wdT,
    const int* __restrict__ btok, const float* __restrict__ bw,
    const int* __restrict__ tile_e, float* __restrict__ yacc)
{
  int mt = blockIdx.x, nt = blockIdx.y;
  int e = tile_e[mt];
  if (e < 0) return;
  __shared__ unsigned short As[128 * 32];
  __shared__ unsigned short Bs[128 * 32];
  int tid = threadIdx.x;
  int wave = tid >> 6, lane = tid & 63;
  int wm = wave >> 1, wn = wave & 1;
  int quad = lane >> 4, l16 = lane & 15;
  int r0 = tid >> 2, r1 = 64 + (tid >> 2);
  int ko = (tid & 3) * 8;
  const unsigned short* gA0 = hbuf + (size_t)(mt * 128 + r0) * I_DIM + ko;
  const unsigned short* gA1 = hbuf + (size_t)(mt * 128 + r1) * I_DIM + ko;
  const unsigned short* bb = wdT + (size_t)e * H_DIM * I_DIM;
  const unsigned short* gB0 = bb + (size_t)(nt * 128 + r0) * I_DIM + ko;
  const unsigned short* gB1 = bb + (size_t)(nt * 128 + r1) * I_DIM + ko;

  f32x4 acc[4][4];
  f32x4 z = {0.f, 0.f, 0.f, 0.f};
#pragma unroll
  for (int i = 0; i < 4; ++i)
#pragma unroll
    for (int j = 0; j < 4; ++j) acc[i][j] = z;

  for (int k0 = 0; k0 < I_DIM; k0 += 32) {
    u16x8 va0 = *(const u16x8*)(gA0 + k0);
    u16x8 va1 = *(const u16x8*)(gA1 + k0);
    u16x8 vb0 = *(const u16x8*)(gB0 + k0);
    u16x8 vb1 = *(const u16x8*)(gB1 + k0);
    *(u16x8*)&As[tid * 8]        = va0;
    *(u16x8*)&As[2048 + tid * 8] = va1;
    *(u16x8*)&Bs[tid * 8]        = vb0;
    *(u16x8*)&Bs[2048 + tid * 8] = vb1;
    __syncthreads();
    bf16x8 af[4];
#pragma unroll
    for (int i = 0; i < 4; ++i)
      af[i] = *(const bf16x8*)&As[(wm * 64 + i * 16 + l16) * 32 + quad * 8];
#pragma unroll
    for (int j = 0; j < 4; ++j) {
      bf16x8 vb = *(const bf16x8*)&Bs[(wn * 64 + j * 16 + l16) * 32 + quad * 8];
#pragma unroll
      for (int i = 0; i < 4; ++i) acc[i][j] = mfma32(af[i], vb, acc[i][j]);
    }
    __syncthreads();
  }
#pragma unroll
  for (int i = 0; i < 4; ++i) {
#pragma unroll
    for (int r = 0; r < 4; ++r) {
      int s = mt * 128 + wm * 64 + i * 16 + quad * 4 + r;
      int t = btok[s]; t = t < 0 ? 0 : (t > N_TOK - 1 ? N_TOK - 1 : t);
      float w = bw[s];                          // 0 for pad slots (memset)
      int colb = nt * 128 + wn * 64 + l16;
#pragma unroll
      for (int j = 0; j < 4; ++j)
        atomicAdd(&yacc[(size_t)t * H_DIM + colb + j * 16], w * acc[i][j][r]);
    }
  }
}

// ---------------- K8: y cast + aux loss (dtype-branched output) ----------------
__global__ __launch_bounds__(256) void k_final(
    const float* __restrict__ yacc, void* __restrict__ out,
    const float* __restrict__ loadw, const int* __restrict__ counts,
    const int* __restrict__ dflag)
{
  bool isf = (*dflag != 0);
  int idx = blockIdx.x * 256 + threadIdx.x;   // 2M threads x 4 elems
  float4 v = ((const float4*)yacc)[idx];
  if (isf) {
    ((float4*)out)[idx] = v;
  } else {
    ushort4 o;
    o.x = f2bf(v.x); o.y = f2bf(v.y); o.z = f2bf(v.z); o.w = f2bf(v.w);
    ((ushort4*)out)[idx] = o;
  }
  if (blockIdx.x == 0 && threadIdx.x == 0) {
    float s = 0.f;
    for (int e = 0; e < 8; ++e) s += loadw[e] * (float)counts[e];
    float aux = s * ((float)N_EXP * 1e-3f) / ((float)N_TOK * (float)N_TOK * (float)TOPK);
    if (isf) ((float*)out)[(size_t)N_TOK * H_DIM] = aux;
    else ((unsigned short*)out)[(size_t)N_TOK * H_DIM] = f2bf(aux);
  }
}

extern "C" void kernel_launch(void* const* d_in, const int* in_sizes, int n_in,
                              void* d_out, int out_size, void* d_ws, size_t ws_size,
                              hipStream_t stream)
{
  (void)in_sizes; (void)n_in; (void)out_size; (void)ws_size;
  const void* x  = d_in[0];
  const void* gw = d_in[1];
  const void* wg = d_in[2];
  const void* wu = d_in[3];
  const void* wd = d_in[4];
  char* ws = (char*)d_ws;

  int*   topk_i = (int*)  (ws + OFF_TOPK_I);
  float* topk_w = (float*)(ws + OFF_TOPK_W);
  int*   counts = (int*)  (ws + OFF_COUNTS);
  float* loadw  = (float*)(ws + OFF_LOAD);
  int*   cursor = (int*)  (ws + OFF_CURSOR);
  int*   po     = (int*)  (ws + OFF_PO);
  int*   tile_e = (int*)  (ws + OFF_TILE_E);
  int*   btok   = (int*)  (ws + OFF_BTOK);
  float* bw     = (float*)(ws + OFF_BW);
  int*   dflag  = (int*)  (ws + OFF_FLAG);
  unsigned short* wgT  = (unsigned short*)(ws + OFF_WGT);
  unsigned short* wuT  = (unsigned short*)(ws + OFF_WUT);
  unsigned short* wdT  = (unsigned short*)(ws + OFF_WDT);
  unsigned short* hbuf = (unsigned short*)(ws + OFF_HB);
  float* yacc = (float*)(ws + OFF_WGT);   // reuse: wgT dead after gemm1

  hipMemsetAsync(ws, 0, CTRL_BYTES, stream);
  k_detect<<<1, 64, 0, stream>>>((const unsigned int*)x, dflag);
  k_transpose<<<12288, 256, 0, stream>>>(wg, wu, wd, wgT, wuT, wdT, dflag);
  k_router<<<N_TOK / 4, 256, 0, stream>>>(x, gw, topk_i, topk_w, counts, loadw, dflag);
  k_offsets<<<1, 256, 0, stream>>>(counts, po, tile_e);
  k_bucket<<<(N_TOK * TOPK) / 256, 256, 0, stream>>>(topk_i, topk_w, po, cursor, btok, bw);
  k_gemm1<<<dim3(MT_MAX, I_DIM / 128), 256, 0, stream>>>(x, wgT, wuT, btok, tile_e, hbuf, dflag);
  hipMemsetAsync(yacc, 0, (size_t)N_TOK * H_DIM * sizeof(float), stream);
  k_gemm2<<<dim3(MT_MAX, H_DIM / 128), 256, 0, stream>>>(hbuf, wdT, btok, bw, tile_e, yacc);
  k_final<<<(N_TOK * H_DIM) / 1024, 256, 0, stream>>>(yacc, d_out, loadw, counts, dflag);
}

// Round 5
// 749.983 us; speedup vs baseline: 1.6387x; 1.6387x over previous
//
#include <hip/hip_runtime.h>

// ---------------- problem constants ----------------
#define N_TOK 8192      // B*S tokens
#define H_DIM 1024
#define I_DIM 2048
#define N_EXP 8
#define TOPK  2
#define CAP   17408     // 16384 + 8*128 (per-expert padding to 128)
#define MT_MAX 136      // CAP / 128

// ---------------- workspace layout (bytes) ----------------
#define OFF_TOPK_I 0u          // 16384 i32
#define OFF_TOPK_W 65536u      // 16384 f32 (RAW softmax probs of chosen experts)
#define OFF_COUNTS 131072u     // 8 i32
#define OFF_LOAD   131104u     // 8 f32
#define OFF_CURSOR 131136u     // 8 i32
#define OFF_PO     131168u     // 16 i32
#define OFF_TILE_E 131232u     // 152 i32 (136 used)
#define OFF_BTOK   131840u     // 17408 i32
#define OFF_BW     201472u     // 17408 f32
#define CTRL_BYTES 271104u
#define OFF_WGT  1048576u                      // 8*2048*1024*2 = 33554432
#define OFF_WUT  (OFF_WGT + 33554432u)
#define OFF_WDT  (OFF_WUT + 33554432u)
#define OFF_HB   (OFF_WDT + 33554432u)         // 17408*2048*2 = 71303168
// y f32 accumulator reuses the WGT region (dead after gemm1)

typedef __attribute__((ext_vector_type(8))) short bf16x8;
typedef __attribute__((ext_vector_type(8))) unsigned short u16x8;
typedef __attribute__((ext_vector_type(4))) float f32x4;

__device__ __forceinline__ unsigned short f2bf(float f) {
  union { float f; unsigned int u; } v; v.f = f;
  unsigned int r = (v.u + 0x7FFFu + ((v.u >> 16) & 1u)) >> 16;
  return (unsigned short)r;
}
__device__ __forceinline__ u16x8 pack8(float4 a, float4 b) {
  u16x8 r;
  r[0] = f2bf(a.x); r[1] = f2bf(a.y); r[2] = f2bf(a.z); r[3] = f2bf(a.w);
  r[4] = f2bf(b.x); r[5] = f2bf(b.y); r[6] = f2bf(b.z); r[7] = f2bf(b.w);
  return r;
}
__device__ __forceinline__ f32x4 mfma32(bf16x8 a, bf16x8 b, f32x4 c) {
  return __builtin_amdgcn_mfma_f32_16x16x32_bf16(a, b, c, 0, 0, 0);
}

// ---------------- K2: tiled transpose f32 -> bf16 of the 3 weight tensors ----------------
// w_gate/w_up [e][1024][2048] -> T [e][2048][1024];  w_down [e][2048][1024] -> T [e][1024][2048]
__global__ __launch_bounds__(256) void k_transpose(
    const float* __restrict__ wg, const float* __restrict__ wu, const float* __restrict__ wd,
    unsigned short* __restrict__ wgT, unsigned short* __restrict__ wuT,
    unsigned short* __restrict__ wdT)
{
  __shared__ unsigned short lds[64][65];
  int bid = blockIdx.x;
  int m = bid / 4096; int rem = bid % 4096;
  const float* src; unsigned short* dst; int R, C;
  if (m == 0)      { src = wg; dst = wgT; R = 1024; C = 2048; }
  else if (m == 1) { src = wu; dst = wuT; R = 1024; C = 2048; }
  else             { src = wd; dst = wdT; R = 2048; C = 1024; }
  int e = rem / 512; int trem = rem % 512;
  int tcc = C / 64;
  int r0 = (trem / tcc) * 64, c0 = (trem % tcc) * 64;
  size_t ebase = (size_t)e * R * C;
  dst += ebase;
  int tid = threadIdx.x;
  int lr = tid >> 3;            // 0..31
  int lc = (tid & 7) * 8;       // 0..56
#pragma unroll
  for (int p = 0; p < 2; ++p) {
    int row = p * 32 + lr;
    size_t off = ebase + (size_t)(r0 + row) * C + c0 + lc;
    float4 q0 = *(const float4*)&src[off];
    float4 q1 = *(const float4*)&src[off + 4];
    unsigned short tmp[8]; *(u16x8*)tmp = pack8(q0, q1);
#pragma unroll
    for (int j = 0; j < 8; ++j) lds[row][lc + j] = tmp[j];
  }
  __syncthreads();
#pragma unroll
  for (int p = 0; p < 2; ++p) {
    int drow = p * 32 + lr;     // local c index
    unsigned short tmp[8];
#pragma unroll
    for (int j = 0; j < 8; ++j) tmp[j] = lds[lc + j][drow];
    *(u16x8*)&dst[(size_t)(c0 + drow) * R + r0 + lc] = *(const u16x8*)tmp;
  }
}

// ---------------- K3: router (1 wave per token, NO global atomics) ----------------
__global__ __launch_bounds__(256) void k_router(
    const float* __restrict__ x, const float* __restrict__ gw,
    int* __restrict__ topk_i, float* __restrict__ topk_w)
{
  int wave = threadIdx.x >> 6, lane = threadIdx.x & 63;
  int t = blockIdx.x * 4 + wave;
  const float* xr = x + (size_t)t * H_DIM;
  float acc[8];
#pragma unroll
  for (int e = 0; e < 8; ++e) acc[e] = 0.f;
#pragma unroll
  for (int it = 0; it < H_DIM / 64; ++it) {
    int h = it * 64 + lane;
    float xv = xr[h];
    float4 g0 = *(const float4*)&gw[h * 8];
    float4 g1 = *(const float4*)&gw[h * 8 + 4];
    acc[0] += xv * g0.x; acc[1] += xv * g0.y; acc[2] += xv * g0.z; acc[3] += xv * g0.w;
    acc[4] += xv * g1.x; acc[5] += xv * g1.y; acc[6] += xv * g1.z; acc[7] += xv * g1.w;
  }
#pragma unroll
  for (int off = 32; off > 0; off >>= 1) {
#pragma unroll
    for (int e = 0; e < 8; ++e) acc[e] += __shfl_xor(acc[e], off);
  }
  if (lane == 0) {
    float m = acc[0];
#pragma unroll
    for (int e = 1; e < 8; ++e) m = fmaxf(m, acc[e]);
    float p[8], s = 0.f;
#pragma unroll
    for (int e = 0; e < 8; ++e) { p[e] = __expf(acc[e] - m); s += p[e]; }
    float inv = 1.f / s;
#pragma unroll
    for (int e = 0; e < 8; ++e) p[e] *= inv;
    int i1 = 0;
#pragma unroll
    for (int e = 1; e < 8; ++e) if (p[e] > p[i1]) i1 = e;   // strict > = lowest-index ties
    int i2 = (i1 == 0) ? 1 : 0;
#pragma unroll
    for (int e = 0; e < 8; ++e) if (e != i1 && p[e] > p[i2]) i2 = e;
    topk_i[t * 2]     = i1; topk_i[t * 2 + 1] = i2;
    topk_w[t * 2]     = p[i1]; topk_w[t * 2 + 1] = p[i2];   // RAW probs
  }
}

// ---------------- K3b: histogram (counts + load) via LDS, few global atomics ----------------
__global__ __launch_bounds__(256) void k_hist(
    const int* __restrict__ topk_i, const float* __restrict__ topk_w,
    int* __restrict__ counts, float* __restrict__ loadw)
{
  __shared__ int c[8]; __shared__ float l[8];
  int tid = threadIdx.x;
  if (tid < 8) { c[tid] = 0; l[tid] = 0.f; }
  __syncthreads();
  int base = blockIdx.x * 1024 + tid * 4;   // 16 blocks cover 16384 entries
#pragma unroll
  for (int j = 0; j < 4; ++j) {
    int e = topk_i[base + j];
    float w = topk_w[base + j];
    atomicAdd(&c[e], 1);
    atomicAdd(&l[e], w);
  }
  __syncthreads();
  if (tid < 8) { atomicAdd(&counts[tid], c[tid]); atomicAdd(&loadw[tid], l[tid]); }
}

// ---------------- K4: padded offsets + tile->expert map ----------------
__global__ __launch_bounds__(256) void k_offsets(const int* __restrict__ counts,
                                                 int* __restrict__ po, int* __restrict__ tile_e)
{
  __shared__ int spo[9];
  if (threadIdx.x == 0) {
    int a = 0;
    for (int e = 0; e < 8; ++e) { spo[e] = a; po[e] = a; a += (counts[e] + 127) & ~127; }
    spo[8] = a; po[8] = a;
  }
  __syncthreads();
  int mt = threadIdx.x;
  if (mt < MT_MAX) {
    int te = -1, beg = mt * 128;
    if (beg < spo[8]) {
      for (int e = 0; e < 8; ++e) if (beg >= spo[e] && beg < spo[e + 1]) te = e;
    }
    tile_e[mt] = te;
  }
}

// ---------------- K5: bucket fill — LDS local ranks, 8 global atomics/block ----------------
__global__ __launch_bounds__(256) void k_bucket(
    const int* __restrict__ topk_i, const float* __restrict__ topk_w,
    const int* __restrict__ po, int* __restrict__ cursor,
    int* __restrict__ btok, float* __restrict__ bw)
{
  __shared__ int c[8];
  __shared__ int basee[8];
  int tid = threadIdx.x;
  if (tid < 8) c[tid] = 0;
  __syncthreads();
  int base = blockIdx.x * 1024 + tid * 4;   // 16 blocks cover 16384 entries
  int e4[4], r4[4]; float w4[4];
#pragma unroll
  for (int j = 0; j < 4; ++j) {
    int idx = base + j;
    int e = topk_i[idx];
    e4[j] = e;
    r4[j] = atomicAdd(&c[e], 1);            // LDS atomic: local rank
    int t = idx >> 1;
    float p0 = topk_w[t * 2], p1 = topk_w[t * 2 + 1];
    w4[j] = topk_w[idx] / (p0 + p1);        // renormalized weight
  }
  __syncthreads();
  if (tid < 8) basee[tid] = po[tid] + atomicAdd(&cursor[tid], c[tid]);
  __syncthreads();
#pragma unroll
  for (int j = 0; j < 4; ++j) {
    int slot = basee[e4[j]] + r4[j];
    btok[slot] = (base + j) >> 1;
    bw[slot] = w4[j];
  }
}

// ---------------- K6: grouped GEMM1, fused gate+up+SiLU -> hbuf bf16 ----------------
__global__ __launch_bounds__(256, 2) void k_gemm1(
    const float* __restrict__ x,
    const unsigned short* __restrict__ wgT, const unsigned short* __restrict__ wuT,
    const int* __restrict__ btok, const int* __restrict__ tile_e,
    unsigned short* __restrict__ hbuf)
{
  int mt = blockIdx.x, nt = blockIdx.y;
  int e = tile_e[mt];
  if (e < 0) return;
  __shared__ unsigned short As[128 * 32];
  __shared__ unsigned short Bg[128 * 32];
  __shared__ unsigned short Bu[128 * 32];
  int tid = threadIdx.x;
  int wave = tid >> 6, lane = tid & 63;
  int wm = wave >> 1, wn = wave & 1;
  int quad = lane >> 4, l16 = lane & 15;

  int r0 = tid >> 2, r1 = 64 + (tid >> 2);
  int ko = (tid & 3) * 8;
  int t0 = btok[mt * 128 + r0]; t0 = t0 < 0 ? 0 : (t0 > N_TOK - 1 ? N_TOK - 1 : t0);
  int t1 = btok[mt * 128 + r1]; t1 = t1 < 0 ? 0 : (t1 > N_TOK - 1 ? N_TOK - 1 : t1);
  const float* gA0 = x + (size_t)t0 * H_DIM + ko;
  const float* gA1 = x + (size_t)t1 * H_DIM + ko;
  const unsigned short* bgb = wgT + (size_t)e * I_DIM * H_DIM;
  const unsigned short* bub = wuT + (size_t)e * I_DIM * H_DIM;
  const unsigned short* gG0 = bgb + (size_t)(nt * 128 + r0) * H_DIM + ko;
  const unsigned short* gG1 = bgb + (size_t)(nt * 128 + r1) * H_DIM + ko;
  const unsigned short* gU0 = bub + (size_t)(nt * 128 + r0) * H_DIM + ko;
  const unsigned short* gU1 = bub + (size_t)(nt * 128 + r1) * H_DIM + ko;

  f32x4 accG[4][4], accU[4][4];
  f32x4 z = {0.f, 0.f, 0.f, 0.f};
#pragma unroll
  for (int i = 0; i < 4; ++i)
#pragma unroll
    for (int j = 0; j < 4; ++j) { accG[i][j] = z; accU[i][j] = z; }

  for (int k0 = 0; k0 < H_DIM; k0 += 32) {
    float4 a00 = *(const float4*)(gA0 + k0);
    float4 a01 = *(const float4*)(gA0 + k0 + 4);
    float4 a10 = *(const float4*)(gA1 + k0);
    float4 a11 = *(const float4*)(gA1 + k0 + 4);
    u16x8 vg0 = *(const u16x8*)(gG0 + k0);
    u16x8 vg1 = *(const u16x8*)(gG1 + k0);
    u16x8 vu0 = *(const u16x8*)(gU0 + k0);
    u16x8 vu1 = *(const u16x8*)(gU1 + k0);
    *(u16x8*)&As[tid * 8]        = pack8(a00, a01);
    *(u16x8*)&As[2048 + tid * 8] = pack8(a10, a11);
    *(u16x8*)&Bg[tid * 8]        = vg0;
    *(u16x8*)&Bg[2048 + tid * 8] = vg1;
    *(u16x8*)&Bu[tid * 8]        = vu0;
    *(u16x8*)&Bu[2048 + tid * 8] = vu1;
    __syncthreads();
    bf16x8 af[4];
#pragma unroll
    for (int i = 0; i < 4; ++i)
      af[i] = *(const bf16x8*)&As[(wm * 64 + i * 16 + l16) * 32 + quad * 8];
#pragma unroll
    for (int j = 0; j < 4; ++j) {
      bf16x8 vg = *(const bf16x8*)&Bg[(wn * 64 + j * 16 + l16) * 32 + quad * 8];
      bf16x8 vu = *(const bf16x8*)&Bu[(wn * 64 + j * 16 + l16) * 32 + quad * 8];
#pragma unroll
      for (int i = 0; i < 4; ++i) {
        accG[i][j] = mfma32(af[i], vg, accG[i][j]);
        accU[i][j] = mfma32(af[i], vu, accU[i][j]);
      }
    }
    __syncthreads();
  }
#pragma unroll
  for (int i = 0; i < 4; ++i) {
#pragma unroll
    for (int r = 0; r < 4; ++r) {
      int row = mt * 128 + wm * 64 + i * 16 + quad * 4 + r;
      size_t base = (size_t)row * I_DIM + nt * 128 + wn * 64 + l16;
#pragma unroll
      for (int j = 0; j < 4; ++j) {
        float g = accG[i][j][r], u = accU[i][j][r];
        float sg = g / (1.f + __expf(-g));    // SiLU
        hbuf[base + j * 16] = f2bf(sg * u);
      }
    }
  }
}

// ---------------- K7: grouped GEMM2, scatter w*val into f32 y accumulator ----------------
__global__ __launch_bounds__(256, 2) void k_gemm2(
    const unsigned short* __restrict__ hbuf, const unsigned short* __restrict__ wdT,
    const int* __restrict__ btok, const float* __restrict__ bw,
    const int* __restrict__ tile_e, float* __restrict__ yacc)
{
  int mt = blockIdx.x, nt = blockIdx.y;
  int e = tile_e[mt];
  if (e < 0) return;
  __shared__ unsigned short As[128 * 32];
  __shared__ unsigned short Bs[128 * 32];
  int tid = threadIdx.x;
  int wave = tid >> 6, lane = tid & 63;
  int wm = wave >> 1, wn = wave & 1;
  int quad = lane >> 4, l16 = lane & 15;
  int r0 = tid >> 2, r1 = 64 + (tid >> 2);
  int ko = (tid & 3) * 8;
  const unsigned short* gA0 = hbuf + (size_t)(mt * 128 + r0) * I_DIM + ko;
  const unsigned short* gA1 = hbuf + (size_t)(mt * 128 + r1) * I_DIM + ko;
  const unsigned short* bb = wdT + (size_t)e * H_DIM * I_DIM;
  const unsigned short* gB0 = bb + (size_t)(nt * 128 + r0) * I_DIM + ko;
  const unsigned short* gB1 = bb + (size_t)(nt * 128 + r1) * I_DIM + ko;

  f32x4 acc[4][4];
  f32x4 z = {0.f, 0.f, 0.f, 0.f};
#pragma unroll
  for (int i = 0; i < 4; ++i)
#pragma unroll
    for (int j = 0; j < 4; ++j) acc[i][j] = z;

  for (int k0 = 0; k0 < I_DIM; k0 += 32) {
    u16x8 va0 = *(const u16x8*)(gA0 + k0);
    u16x8 va1 = *(const u16x8*)(gA1 + k0);
    u16x8 vb0 = *(const u16x8*)(gB0 + k0);
    u16x8 vb1 = *(const u16x8*)(gB1 + k0);
    *(u16x8*)&As[tid * 8]        = va0;
    *(u16x8*)&As[2048 + tid * 8] = va1;
    *(u16x8*)&Bs[tid * 8]        = vb0;
    *(u16x8*)&Bs[2048 + tid * 8] = vb1;
    __syncthreads();
    bf16x8 af[4];
#pragma unroll
    for (int i = 0; i < 4; ++i)
      af[i] = *(const bf16x8*)&As[(wm * 64 + i * 16 + l16) * 32 + quad * 8];
#pragma unroll
    for (int j = 0; j < 4; ++j) {
      bf16x8 vb = *(const bf16x8*)&Bs[(wn * 64 + j * 16 + l16) * 32 + quad * 8];
#pragma unroll
      for (int i = 0; i < 4; ++i) acc[i][j] = mfma32(af[i], vb, acc[i][j]);
    }
    __syncthreads();
  }
#pragma unroll
  for (int i = 0; i < 4; ++i) {
#pragma unroll
    for (int r = 0; r < 4; ++r) {
      int s = mt * 128 + wm * 64 + i * 16 + quad * 4 + r;
      int t = btok[s]; t = t < 0 ? 0 : (t > N_TOK - 1 ? N_TOK - 1 : t);
      float w = bw[s];                          // 0 for pad slots (memset)
      int colb = nt * 128 + wn * 64 + l16;
#pragma unroll
      for (int j = 0; j < 4; ++j)
        atomicAdd(&yacc[(size_t)t * H_DIM + colb + j * 16], w * acc[i][j][r]);
    }
  }
}

// ---------------- K8: y copy (f32) + aux loss ----------------
__global__ __launch_bounds__(256) void k_final(
    const float* __restrict__ yacc, float* __restrict__ out,
    const float* __restrict__ loadw, const int* __restrict__ counts)
{
  int idx = blockIdx.x * 256 + threadIdx.x;   // 2M threads x 4 elems
  float4 v = ((const float4*)yacc)[idx];
  ((float4*)out)[idx] = v;
  if (blockIdx.x == 0 && threadIdx.x == 0) {
    float s = 0.f;
    for (int e = 0; e < 8; ++e) s += loadw[e] * (float)counts[e];
    float aux = s * ((float)N_EXP * 1e-3f) / ((float)N_TOK * (float)N_TOK * (float)TOPK);
    out[(size_t)N_TOK * H_DIM] = aux;
  }
}

extern "C" void kernel_launch(void* const* d_in, const int* in_sizes, int n_in,
                              void* d_out, int out_size, void* d_ws, size_t ws_size,
                              hipStream_t stream)
{
  (void)in_sizes; (void)n_in; (void)out_size; (void)ws_size;
  const float* x  = (const float*)d_in[0];
  const float* gw = (const float*)d_in[1];
  const float* wg = (const float*)d_in[2];
  const float* wu = (const float*)d_in[3];
  const float* wd = (const float*)d_in[4];
  char* ws = (char*)d_ws;

  int*   topk_i = (int*)  (ws + OFF_TOPK_I);
  float* topk_w = (float*)(ws + OFF_TOPK_W);
  int*   counts = (int*)  (ws + OFF_COUNTS);
  float* loadw  = (float*)(ws + OFF_LOAD);
  int*   cursor = (int*)  (ws + OFF_CURSOR);
  int*   po     = (int*)  (ws + OFF_PO);
  int*   tile_e = (int*)  (ws + OFF_TILE_E);
  int*   btok   = (int*)  (ws + OFF_BTOK);
  float* bw     = (float*)(ws + OFF_BW);
  unsigned short* wgT  = (unsigned short*)(ws + OFF_WGT);
  unsigned short* wuT  = (unsigned short*)(ws + OFF_WUT);
  unsigned short* wdT  = (unsigned short*)(ws + OFF_WDT);
  unsigned short* hbuf = (unsigned short*)(ws + OFF_HB);
  float* yacc = (float*)(ws + OFF_WGT);   // reuse: wgT dead after gemm1

  (void)hipMemsetAsync(ws, 0, CTRL_BYTES, stream);
  k_transpose<<<12288, 256, 0, stream>>>(wg, wu, wd, wgT, wuT, wdT);
  k_router<<<N_TOK / 4, 256, 0, stream>>>(x, gw, topk_i, topk_w);
  k_hist<<<16, 256, 0, stream>>>(topk_i, topk_w, counts, loadw);
  k_offsets<<<1, 256, 0, stream>>>(counts, po, tile_e);
  k_bucket<<<16, 256, 0, stream>>>(topk_i, topk_w, po, cursor, btok, bw);
  k_gemm1<<<dim3(MT_MAX, I_DIM / 128), 256, 0, stream>>>(x, wgT, wuT, btok, tile_e, hbuf);
  (void)hipMemsetAsync(yacc, 0, (size_t)N_TOK * H_DIM * sizeof(float), stream);
  k_gemm2<<<dim3(MT_MAX, H_DIM / 128), 256, 0, stream>>>(hbuf, wdT, btok, bw, tile_e, yacc);
  k_final<<<(N_TOK * H_DIM) / 1024, 256, 0, stream>>>(yacc, (float*)d_out, loadw, counts);
}